// Round 1
// baseline (1722.511 us; speedup 1.0000x reference)
//
#include <hip/hip_runtime.h>

// SFNO block on MI355X. All heavy stages as bf16 MFMA GEMMs (C = A * B^T),
// fp32 accumulate. Complex tensors stored as separate real/imag planes.
// Sizes: C=256, NLAT=256, NLON=512, L=256, M=257 (padded ld 264), NREF=64.

typedef __bf16 bf16x8 __attribute__((ext_vector_type(8)));
typedef float f32x4 __attribute__((ext_vector_type(4)));
typedef unsigned short u16;
typedef unsigned int u32;

__device__ __forceinline__ u16 f2b(float f){
  u32 u = __float_as_uint(f);
  u32 r = (u + 0x7FFFu + ((u >> 16) & 1u)) >> 16;  // round-to-nearest-even
  return (u16)r;
}
__device__ __forceinline__ float gelu_exact(float v){
  return 0.5f * v * (1.0f + erff(v * 0.7071067811865475f));
}

// ---------------- small precompute kernels ----------------

// forward DFT tables: Tc[m][n]=cos(2pi m n/512), Ts[m][n]=-sin(...), (257 x 512) bf16
__global__ __launch_bounds__(256) void k_ftab(u16* Tc, u16* Ts){
  int i = blockIdx.x*256 + threadIdx.x;
  if (i >= 257*512) return;
  int m = i >> 9, n = i & 511;
  int r = (m*n) & 511;
  float th = (float)r * (6.283185307179586f/512.0f);
  Tc[i] = f2b(cosf(th));
  Ts[i] = f2b(-sinf(th));
}
// inverse tables (512 x 264), col-padded zero. cm=1 for m in {0,256}, else 2; /512.
__global__ __launch_bounds__(256) void k_itab(u16* tr, u16* ti){
  int i = blockIdx.x*256 + threadIdx.x;
  if (i >= 512*264) return;
  int n = i / 264, m = i % 264;
  if (m >= 257){ tr[i]=0; ti[i]=0; return; }
  int r = (n*m) & 511;
  float th = (float)r * (6.283185307179586f/512.0f);
  float cm = (m==0 || m==256) ? (1.0f/512.0f) : (2.0f/512.0f);
  tr[i] = f2b(cm*cosf(th));
  ti[i] = f2b(-cm*sinf(th));
}
// lw[l,m,j] = legfuncs[l,m,j]*wquad[j] -> bf16, same layout (j innermost, 256)
__global__ __launch_bounds__(256) void k_lw(const float* __restrict__ leg,
                                            const float* __restrict__ wq,
                                            u16* __restrict__ lw, int total){
  int i = blockIdx.x*256 + threadIdx.x;
  if (i >= total) return;
  lw[i] = f2b(leg[i]*wq[i & 255]);
}
// interpolated filters, scaled by sqrt(1+l)/256, layout (l,f,c) bf16
__global__ __launch_bounds__(256) void k_interp(const float* __restrict__ wr,
                                                const float* __restrict__ wi,
                                                u16* __restrict__ Wr2, u16* __restrict__ Wi2){
  int i = blockIdx.x*256 + threadIdx.x;
  if (i >= 256*256*256) return;
  int c = i & 255, f = (i>>8) & 255, l = i >> 16;
  float pos = (float)l * (63.0f/255.0f);
  int i0 = (int)floorf(pos); i0 = min(max(i0,0),62);
  float fr = pos - (float)i0;
  float s = sqrtf(1.0f + (float)l) * (1.0f/256.0f);
  long long wbase = ((long long)(f*256 + c))*64 + i0;
  Wr2[i] = f2b((wr[wbase]*(1.0f-fr) + wr[wbase+1]*fr) * s);
  Wi2[i] = f2b((wi[wbase]*(1.0f-fr) + wi[wbase+1]*fr) * s);
}

// ---------------- generic tiled transposes ----------------
// dst[b*ob + c*oc + r] = cvt(src[b*ib + r*ir + c]); src contiguous in c, dst in r.
template<bool DUAL>
__global__ __launch_bounds__(256)
void tr_f32b(const float* __restrict__ src, u16* __restrict__ dst, u16* __restrict__ copy,
             int R, int Cc, long long ir, long long ib, long long oc, long long ob){
  __shared__ float tile[32][33];
  const long long b = blockIdx.z;
  const int r0 = blockIdx.y*32, c0 = blockIdx.x*32;
  const int tx = threadIdx.x & 31, ty = threadIdx.x >> 5;
  const float* s = src + b*ib;
  #pragma unroll
  for (int rr = ty; rr < 32; rr += 8){
    int r = r0 + rr, c = c0 + tx;
    float v = 0.0f;
    if (r < R && c < Cc){
      v = s[(long long)r*ir + c];
      if (DUAL) copy[b*ib + (long long)r*ir + c] = f2b(v);
    }
    tile[rr][tx] = v;
  }
  __syncthreads();
  u16* d = dst + b*ob;
  #pragma unroll
  for (int cc = ty; cc < 32; cc += 8){
    int c = c0 + cc, r = r0 + tx;
    if (r < R && c < Cc) d[(long long)c*oc + r] = f2b(tile[tx][cc]);
  }
}
__global__ __launch_bounds__(256)
void tr_b16(const u16* __restrict__ src, u16* __restrict__ dst,
            int R, int Cc, long long ir, long long ib, long long oc, long long ob){
  __shared__ u16 tile[32][34];
  const long long b = blockIdx.z;
  const int r0 = blockIdx.y*32, c0 = blockIdx.x*32;
  const int tx = threadIdx.x & 31, ty = threadIdx.x >> 5;
  const u16* s = src + b*ib;
  #pragma unroll
  for (int rr = ty; rr < 32; rr += 8){
    int r = r0 + rr, c = c0 + tx;
    tile[rr][tx] = (r < R && c < Cc) ? s[(long long)r*ir + c] : (u16)0;
  }
  __syncthreads();
  u16* d = dst + b*ob;
  #pragma unroll
  for (int cc = ty; cc < 32; cc += 8){
    int c = c0 + cc, r = r0 + tx;
    if (r < R && c < Cc) d[(long long)c*oc + r] = tile[tx][cc];
  }
}

// ---------------- the GEMM ----------------
// MODE 0: C0 = A0*B0^T
// MODE 1: C0 = A0*B0^T ; C1 = A1*B1^T       (share either operand by passing same ptr)
// MODE 2: C0 = A0*B0^T - A1*B1^T ; C1 = A0*B1^T + A1*B0^T   (complex)
// MODE 3: C0 = A0*B0^T + A1*B1^T            (irfft)
// EPI 0: store bf16 raw (C0[,C1]); 2: bf16 gelu(v+bias); 3: bf16 gelu(v+bias)+addsrc;
// EPI 4: f32 gelu(v); 5: f32 gelu(v+bias)
struct GemmP {
  const u16 *A0, *A1, *B0, *B1;
  void *C0, *C1;
  const float *bias;
  const float *addsrc;
  int M, N, K;
  int lda, ldb, ldc;
  long long bsA, bsB, bsC;
};

#define LDT 56   // LDS row stride (bf16 elems): 112B rows -> 16B aligned, 2-way banks max

__device__ __forceinline__ void stage_tile(u16* s, const u16* g, int ld, int grow,
                                           int rmax, int kc, int K, int srow, int scg){
  u16* dst = s + srow*LDT + scg;
  if (grow < rmax && kc + 8 <= K){
    *(uint4*)dst = *(const uint4*)(g + (long long)grow*ld + kc);
  } else {
    u16 v[8];
    #pragma unroll
    for (int j=0;j<8;j++)
      v[j] = (grow < rmax && kc + j < K) ? g[(long long)grow*ld + kc + j] : (u16)0;
    *(uint4*)dst = *(const uint4*)v;
  }
}

template<int MODE, int EPI>
__global__ __launch_bounds__(256)
void gemm_bt(GemmP p){
  constexpr int NT = (MODE >= 1) ? 2 : 1;
  __shared__ u16 sA[NT*64*LDT];
  __shared__ u16 sB[NT*64*LDT];
  const int tid = threadIdx.x;
  const long long bz = blockIdx.z;
  const u16* Ap[2]; const u16* Bp[2];
  Ap[0] = p.A0 + bz*p.bsA; Bp[0] = p.B0 + bz*p.bsB;
  if (NT == 2){ Ap[1] = p.A1 + bz*p.bsA; Bp[1] = p.B1 + bz*p.bsB; }
  const int row0 = blockIdx.y*64, col0 = blockIdx.x*64;
  const int srow = tid >> 2, scg = (tid & 3) << 3;
  const int lane = tid & 63, wid = tid >> 6;
  const int wr = wid >> 1, wc = wid & 1;
  const int quad = lane >> 4, l15 = lane & 15;

  f32x4 acc0[2][2], acc1[2][2], acc2[2][2];
  #pragma unroll
  for (int i=0;i<2;i++)
    #pragma unroll
    for (int j=0;j<2;j++){
      acc0[i][j] = (f32x4){0.f,0.f,0.f,0.f};
      acc1[i][j] = (f32x4){0.f,0.f,0.f,0.f};
      acc2[i][j] = (f32x4){0.f,0.f,0.f,0.f};
    }

  for (int k0 = 0; k0 < p.K; k0 += 32){
    __syncthreads();
    #pragma unroll
    for (int t=0;t<NT;t++){
      stage_tile(sA + t*64*LDT, Ap[t], p.lda, row0 + srow, p.M, k0 + scg, p.K, srow, scg);
      stage_tile(sB + t*64*LDT, Bp[t], p.ldb, col0 + srow, p.N, k0 + scg, p.K, srow, scg);
    }
    __syncthreads();
    bf16x8 af[NT][2], bg[NT][2];
    #pragma unroll
    for (int t=0;t<NT;t++){
      #pragma unroll
      for (int i=0;i<2;i++){
        af[t][i] = *(const bf16x8*)&sA[t*64*LDT + (wr*32 + i*16 + l15)*LDT + quad*8];
        bg[t][i] = *(const bf16x8*)&sB[t*64*LDT + (wc*32 + i*16 + l15)*LDT + quad*8];
      }
    }
    #pragma unroll
    for (int i=0;i<2;i++){
      #pragma unroll
      for (int j=0;j<2;j++){
        if (MODE == 0){
          acc0[i][j] = __builtin_amdgcn_mfma_f32_16x16x32_bf16(af[0][i], bg[0][j], acc0[i][j], 0,0,0);
        } else if (MODE == 1){
          acc0[i][j] = __builtin_amdgcn_mfma_f32_16x16x32_bf16(af[0][i], bg[0][j], acc0[i][j], 0,0,0);
          acc1[i][j] = __builtin_amdgcn_mfma_f32_16x16x32_bf16(af[1][i], bg[1][j], acc1[i][j], 0,0,0);
        } else if (MODE == 2){
          acc0[i][j] = __builtin_amdgcn_mfma_f32_16x16x32_bf16(af[0][i], bg[0][j], acc0[i][j], 0,0,0);
          acc1[i][j] = __builtin_amdgcn_mfma_f32_16x16x32_bf16(af[1][i], bg[1][j], acc1[i][j], 0,0,0);
          acc2[i][j] = __builtin_amdgcn_mfma_f32_16x16x32_bf16(af[0][i], bg[1][j], acc2[i][j], 0,0,0);
          acc2[i][j] = __builtin_amdgcn_mfma_f32_16x16x32_bf16(af[1][i], bg[0][j], acc2[i][j], 0,0,0);
        } else {
          acc0[i][j] = __builtin_amdgcn_mfma_f32_16x16x32_bf16(af[0][i], bg[0][j], acc0[i][j], 0,0,0);
          acc0[i][j] = __builtin_amdgcn_mfma_f32_16x16x32_bf16(af[1][i], bg[1][j], acc0[i][j], 0,0,0);
        }
      }
    }
  }

  const long long cb = bz * p.bsC;
  #pragma unroll
  for (int i=0;i<2;i++){
    #pragma unroll
    for (int j=0;j<2;j++){
      const int gr0 = row0 + wr*32 + i*16 + quad*4;
      const int gc  = col0 + wc*32 + j*16 + l15;
      if (gc >= p.N) continue;
      #pragma unroll
      for (int r=0;r<4;r++){
        const int gr = gr0 + r;
        if (gr >= p.M) continue;
        const long long ci = cb + (long long)gr * p.ldc + gc;
        float v0, v1 = 0.0f;
        if (MODE == 2){ v0 = acc0[i][j][r] - acc1[i][j][r]; v1 = acc2[i][j][r]; }
        else { v0 = acc0[i][j][r]; if (MODE == 1) v1 = acc1[i][j][r]; }
        if (EPI == 0){
          ((u16*)p.C0)[ci] = f2b(v0);
          if (MODE == 1 || MODE == 2) ((u16*)p.C1)[ci] = f2b(v1);
        } else if (EPI == 2){
          ((u16*)p.C0)[ci] = f2b(gelu_exact(v0 + p.bias[gc]));
        } else if (EPI == 3){
          ((u16*)p.C0)[ci] = f2b(gelu_exact(v0 + p.bias[gc]) + p.addsrc[ci]);
        } else if (EPI == 4){
          ((float*)p.C0)[ci] = gelu_exact(v0);
        } else if (EPI == 5){
          ((float*)p.C0)[ci] = gelu_exact(v0 + p.bias[gc]);
        }
      }
    }
  }
}

// ---------------- instance-norm reduction + final epilogue ----------------
__global__ __launch_bounds__(256) void k_red(const float* __restrict__ y2,
                                             float* __restrict__ gs, float* __restrict__ gss){
  int t = threadIdx.x;
  long long r0 = (long long)blockIdx.x * 256;
  float s = 0.f, ss = 0.f;
  for (int r=0;r<256;r++){
    float v = y2[(r0 + r)*256 + t];
    s += v; ss += v*v;
  }
  atomicAdd(&gs[t], s);
  atomicAdd(&gss[t], ss);
}
// out[c,j,n] = (y2[n,j,c]-mu)*rsqrt(var+eps)*gamma + beta + x[c,j,n]
__global__ __launch_bounds__(256) void k_out(const float* __restrict__ y2, const float* __restrict__ x,
                                             const float* __restrict__ gs, const float* __restrict__ gss,
                                             const float* __restrict__ gamma, const float* __restrict__ beta,
                                             float* __restrict__ out){
  __shared__ float tile[32][33];
  const int j = blockIdx.z;
  const int n0 = blockIdx.x*32, c0 = blockIdx.y*32;
  const int tx = threadIdx.x & 31, ty = threadIdx.x >> 5;
  #pragma unroll
  for (int nn = ty; nn < 32; nn += 8){
    int n = n0 + nn, c = c0 + tx;
    tile[nn][tx] = y2[(long long)n*65536 + j*256 + c];
  }
  __syncthreads();
  #pragma unroll
  for (int cc = ty; cc < 32; cc += 8){
    int c = c0 + cc, n = n0 + tx;
    float mu = gs[c]*(1.0f/131072.0f);
    float var = gss[c]*(1.0f/131072.0f) - mu*mu;
    float rs = rsqrtf(var + 1e-3f);
    long long oi = (long long)c*131072 + (long long)j*512 + n;
    out[oi] = (tile[tx][cc] - mu)*rs*gamma[c] + beta[c] + x[oi];
  }
}

// ---------------- host ----------------
extern "C" void kernel_launch(void* const* d_in, const int* in_sizes, int n_in,
                              void* d_out, int out_size, void* d_ws, size_t ws_size,
                              hipStream_t stream){
  (void)in_sizes; (void)n_in; (void)out_size; (void)ws_size;
  const float* x     = (const float*)d_in[0];
  const float* legf  = (const float*)d_in[1];
  const float* wq    = (const float*)d_in[2];
  const float* w_r   = (const float*)d_in[3];
  const float* w_i   = (const float*)d_in[4];
  const float* m1w1  = (const float*)d_in[5];
  const float* m1b1  = (const float*)d_in[6];
  const float* m1w2  = (const float*)d_in[7];
  const float* m1b2  = (const float*)d_in[8];
  const float* m2w1  = (const float*)d_in[9];
  const float* m2b1  = (const float*)d_in[10];
  const float* m2w2  = (const float*)d_in[11];
  const float* m2b2  = (const float*)d_in[12];
  const float* gamma = (const float*)d_in[13];
  const float* beta  = (const float*)d_in[14];

  char* ws = (char*)d_ws;
  const size_t SLOT = 73400320ULL, HS = 36700160ULL;
  char* F  = ws;                    // small fixed region (4MB)
  char* SA = ws + 4194304ULL;
  char* SB = SA + SLOT;
  char* SC = SB + SLOT;
  char* SD = SC + SLOT;             // total ~284MB

  u16* Tc   = (u16*)(F + 0x000000);
  u16* Ts   = (u16*)(F + 0x050000);
  u16* tabr = (u16*)(F + 0x0A0000);
  u16* tabi = (u16*)(F + 0x0F0000);
  u16* w1t  = (u16*)(F + 0x140000);
  u16* w2t  = (u16*)(F + 0x160000);
  u16* w3t  = (u16*)(F + 0x180000);
  u16* w4t  = (u16*)(F + 0x1A0000);
  float* gsum = (float*)(F + 0x1C0000);
  float* gssq = (float*)(F + 0x1C0400);

  u16* xT   = (u16*)SA;            // (n,j,c) bf16, lives until MLP1a
  u16* x_bf = (u16*)SB;            // (c,j,n) bf16
  u16* lw   = (u16*)SC;            // (l,m,j) bf16
  u16* Fr2  = (u16*)SD;            // (m,c,j) bf16
  u16* Fi2  = (u16*)(SD + HS);
  u16* hr3  = (u16*)SB;            // (m,l,c) bf16  (over x_bf)
  u16* hi3  = (u16*)(SB + HS);
  u16* Wr2  = (u16*)SD;            // (l,f,c) bf16  (over F2)
  u16* Wi2  = (u16*)(SD + HS);
  u16* xs3r = (u16*)SC;            // (l,f,m) ld 264 (over lw)
  u16* xs3i = (u16*)(SC + HS);
  u16* legT = (u16*)SB;            // (m,j,l) bf16  (over h3)
  u16* xs4r = (u16*)SD;            // (m,f,l)       (over W2)
  u16* xs4i = (u16*)(SD + HS);
  u16* Gr5  = (u16*)SC;            // (m,f,j)       (over xs3)
  u16* Gi5  = (u16*)(SC + HS);
  u16* Gr6  = (u16*)SD;            // (j,f,m) ld 264 (over xs4)
  u16* Gi6  = (u16*)(SD + HS);
  float* g6 = (float*)SB;          // (n,j,f) f32, spans B+C
  u16* h1   = (u16*)SD;            // (p,c) bf16    (over G6)
  u16* addb = (u16*)SA;            // (p,c) bf16    (over xT)
  u16* h2   = (u16*)SD;            // (over h1)
  float* y2 = (float*)SB;          // (p,c) f32, spans B+C (over g6)

  auto launch_gemm = [&](auto kern, int M, int N, int K,
                         const u16* A0, const u16* A1, long long bsA, int lda,
                         const u16* B0, const u16* B1, long long bsB, int ldb,
                         void* C0, void* C1, long long bsC, int ldc,
                         const float* bias, const float* addsrc, int batch){
    GemmP p{A0, A1, B0, B1, C0, C1, bias, addsrc, M, N, K, lda, ldb, ldc, bsA, bsB, bsC};
    dim3 g((unsigned)((N+63)/64), (unsigned)((M+63)/64), (unsigned)batch);
    kern<<<g, dim3(256), 0, stream>>>(p);
  };

  // --- precompute ---
  k_ftab<<<dim3(514), dim3(256), 0, stream>>>(Tc, Ts);
  k_itab<<<dim3(528), dim3(256), 0, stream>>>(tabr, tabi);
  // MLP weight transposes (ci,co)->(co,ci)
  tr_f32b<false><<<dim3(8,8,1), dim3(256), 0, stream>>>(m1w1, w1t, nullptr, 256,256, 256,0, 256,0);
  tr_f32b<false><<<dim3(8,8,1), dim3(256), 0, stream>>>(m1w2, w2t, nullptr, 256,256, 256,0, 256,0);
  tr_f32b<false><<<dim3(8,8,1), dim3(256), 0, stream>>>(m2w1, w3t, nullptr, 256,256, 256,0, 256,0);
  tr_f32b<false><<<dim3(8,8,1), dim3(256), 0, stream>>>(m2w2, w4t, nullptr, 256,256, 256,0, 256,0);
  // x (c,j,n) -> xT (n,j,c) bf16 + straight bf16 copy x_bf
  tr_f32b<true><<<dim3(16,8,256), dim3(256), 0, stream>>>(x, xT, x_bf, 256,512, 131072,512, 65536,256);
  // lw
  k_lw<<<dim3(65792), dim3(256), 0, stream>>>(legf, wq, lw, 256*257*256);

  // --- stage 1: rfft. Fr/Fi (m,c,j) = T (m,n) * x_bf^T ---
  launch_gemm(gemm_bt<1,0>, 257, 65536, 512,
              Tc, Ts, 0, 512,  x_bf, x_bf, 0, 512,
              Fr2, Fi2, 0, 65536, nullptr, nullptr, 1);
  // --- stage 2: Legendre fwd, batched over m: h(m,l,c) = lw_m (l,j) * F_m(c,j)^T ---
  launch_gemm(gemm_bt<1,0>, 256, 256, 256,
              lw, lw, 256, 65792,  Fr2, Fi2, 65536, 256,
              hr3, hi3, 65536, 256, nullptr, nullptr, 257);
  // --- filters (after F2 dead) ---
  k_interp<<<dim3(65536), dim3(256), 0, stream>>>(w_r, w_i, Wr2, Wi2);
  // --- stage 3: complex filter, batched over l: xs(l,f,m) = W_l(f,c) * h_l(m,c)^T ---
  launch_gemm(gemm_bt<2,0>, 256, 257, 256,
              Wr2, Wi2, 65536, 256,  hr3, hi3, 256, 65536,
              xs3r, xs3i, 67584, 264, nullptr, nullptr, 256);
  // --- legT (m,j,l) (after h3 dead) ---
  tr_f32b<false><<<dim3(8,8,257), dim3(256), 0, stream>>>(legf, legT, nullptr, 256,256, 65792,256, 256,65536);
  // --- xs (l,f,m) -> (m,f,l) ---
  tr_b16<<<dim3(9,8,256), dim3(256), 0, stream>>>(xs3r, xs4r, 256,257, 67584,264, 65536,256);
  tr_b16<<<dim3(9,8,256), dim3(256), 0, stream>>>(xs3i, xs4i, 256,257, 67584,264, 65536,256);
  // --- stage 4: Legendre inv, batched over m: G(m,f,j) = xs_m(f,l) * legT_m(j,l)^T ---
  launch_gemm(gemm_bt<1,0>, 256, 256, 256,
              xs4r, xs4i, 65536, 256,  legT, legT, 65536, 256,
              Gr5, Gi5, 65536, 256, nullptr, nullptr, 257);
  // --- G (m,f,j) -> (j,f,m) ---
  tr_b16<<<dim3(8,9,256), dim3(256), 0, stream>>>(Gr5, Gr6, 257,256, 65536,256, 67584,264);
  tr_b16<<<dim3(8,9,256), dim3(256), 0, stream>>>(Gi5, Gi6, 257,256, 65536,256, 67584,264);
  // --- stage 5: irfft + gelu: g6 (n, jf) = tabr(n,m)*Gr6^T + tabi(n,m)*Gi6^T ---
  launch_gemm(gemm_bt<3,4>, 512, 65536, 257,
              tabr, tabi, 0, 264,  Gr6, Gi6, 0, 264,
              g6, nullptr, 0, 65536, nullptr, nullptr, 1);
  // --- MLP1 ---
  launch_gemm(gemm_bt<0,2>, 131072, 256, 256,
              xT, nullptr, 0, 256,  w1t, nullptr, 0, 256,
              h1, nullptr, 0, 256, m1b1, nullptr, 1);
  launch_gemm(gemm_bt<0,3>, 131072, 256, 256,
              h1, nullptr, 0, 256,  w2t, nullptr, 0, 256,
              addb, nullptr, 0, 256, m1b2, g6, 1);
  // --- MLP2 ---
  launch_gemm(gemm_bt<0,2>, 131072, 256, 256,
              addb, nullptr, 0, 256,  w3t, nullptr, 0, 256,
              h2, nullptr, 0, 256, m2b1, nullptr, 1);
  launch_gemm(gemm_bt<0,5>, 131072, 256, 256,
              h2, nullptr, 0, 256,  w4t, nullptr, 0, 256,
              y2, nullptr, 0, 256, m2b2, nullptr, 1);
  // --- instance norm + residual ---
  hipMemsetAsync(gsum, 0, 2048, stream);   // zeroes gsum+gssq
  k_red<<<dim3(512), dim3(256), 0, stream>>>(y2, gsum, gssq);
  k_out<<<dim3(16,8,256), dim3(256), 0, stream>>>(y2, x, gsum, gssq, gamma, beta, (float*)d_out);
}

// Round 2
// 1609.305 us; speedup vs baseline: 1.0703x; 1.0703x over previous
//
#include <hip/hip_runtime.h>

// SFNO block on MI355X. All heavy stages as bf16 MFMA GEMMs (C = A * B^T),
// fp32 accumulate, 128x128 tiles, global_load_lds staging, XOR-swizzled LDS.
// Sizes: C=256, NLAT=256, NLON=512, L=256, M=257 (padded ld 264), NREF=64.

typedef __bf16 bf16x8 __attribute__((ext_vector_type(8)));
typedef float f32x4 __attribute__((ext_vector_type(4)));
typedef unsigned short u16;
typedef unsigned int u32;

__device__ __forceinline__ u16 f2b(float f){
  u32 u = __float_as_uint(f);
  u32 r = (u + 0x7FFFu + ((u >> 16) & 1u)) >> 16;  // round-to-nearest-even
  return (u16)r;
}
__device__ __forceinline__ float b2f(u16 h){
  return __uint_as_float(((u32)h) << 16);
}
__device__ __forceinline__ float gelu_exact(float v){
  return 0.5f * v * (1.0f + erff(v * 0.7071067811865475f));
}

// ---------------- small precompute kernels ----------------

// forward DFT tables (257 x 512) bf16: Tc=cos(2pi m n/512), Ts=-sin(...)
__global__ __launch_bounds__(256) void k_ftab(u16* Tc, u16* Ts){
  int i = blockIdx.x*256 + threadIdx.x;
  if (i >= 257*512) return;
  int m = i >> 9, n = i & 511;
  int r = (m*n) & 511;
  float th = (float)r * (6.283185307179586f/512.0f);
  Tc[i] = f2b(cosf(th));
  Ts[i] = f2b(-sinf(th));
}
// inverse tables (512 x 264), cols >=257 zero. cm=1 for m in {0,256}, else 2; /512.
__global__ __launch_bounds__(256) void k_itab(u16* tr, u16* ti){
  int i = blockIdx.x*256 + threadIdx.x;
  if (i >= 512*264) return;
  int n = i / 264, m = i % 264;
  if (m >= 257){ tr[i]=0; ti[i]=0; return; }
  int r = (n*m) & 511;
  float th = (float)r * (6.283185307179586f/512.0f);
  float cm = (m==0 || m==256) ? (1.0f/512.0f) : (2.0f/512.0f);
  tr[i] = f2b(cm*cosf(th));
  ti[i] = f2b(-cm*sinf(th));
}
// lw[l,m,j] = legfuncs[l,m,j]*wquad[j] -> bf16
__global__ __launch_bounds__(256) void k_lw(const float* __restrict__ leg,
                                            const float* __restrict__ wq,
                                            u16* __restrict__ lw, int total){
  int i = blockIdx.x*256 + threadIdx.x;
  if (i >= total) return;
  lw[i] = f2b(leg[i]*wq[i & 255]);
}
// interpolated filters, scaled by sqrt(1+l)/256, layout (l,f,c) bf16
__global__ __launch_bounds__(256) void k_interp(const float* __restrict__ wr,
                                                const float* __restrict__ wi,
                                                u16* __restrict__ Wr2, u16* __restrict__ Wi2){
  int i = blockIdx.x*256 + threadIdx.x;
  if (i >= 256*256*256) return;
  int c = i & 255, f = (i>>8) & 255, l = i >> 16;
  float pos = (float)l * (63.0f/255.0f);
  int i0 = (int)floorf(pos); i0 = min(max(i0,0),62);
  float fr = pos - (float)i0;
  float s = sqrtf(1.0f + (float)l) * (1.0f/256.0f);
  long long wbase = ((long long)(f*256 + c))*64 + i0;
  Wr2[i] = f2b((wr[wbase]*(1.0f-fr) + wr[wbase+1]*fr) * s);
  Wi2[i] = f2b((wi[wbase]*(1.0f-fr) + wi[wbase+1]*fr) * s);
}

// ---------------- generic tiled transposes ----------------
template<bool DUAL>
__global__ __launch_bounds__(256)
void tr_f32b(const float* __restrict__ src, u16* __restrict__ dst, u16* __restrict__ copy,
             int R, int Cc, long long ir, long long ib, long long oc, long long ob){
  __shared__ float tile[32][33];
  const long long b = blockIdx.z;
  const int r0 = blockIdx.y*32, c0 = blockIdx.x*32;
  const int tx = threadIdx.x & 31, ty = threadIdx.x >> 5;
  const float* s = src + b*ib;
  #pragma unroll
  for (int rr = ty; rr < 32; rr += 8){
    int r = r0 + rr, c = c0 + tx;
    float v = 0.0f;
    if (r < R && c < Cc){
      v = s[(long long)r*ir + c];
      if (DUAL) copy[b*ib + (long long)r*ir + c] = f2b(v);
    }
    tile[rr][tx] = v;
  }
  __syncthreads();
  u16* d = dst + b*ob;
  #pragma unroll
  for (int cc = ty; cc < 32; cc += 8){
    int c = c0 + cc, r = r0 + tx;
    if (r < R && c < Cc) d[(long long)c*oc + r] = f2b(tile[tx][cc]);
  }
}
// bf16 transpose; zero-pads dst rows r in [R, Rpad)
__global__ __launch_bounds__(256)
void tr_b16(const u16* __restrict__ src, u16* __restrict__ dst,
            int R, int Rpad, int Cc, long long ir, long long ib, long long oc, long long ob){
  __shared__ u16 tile[32][34];
  const long long b = blockIdx.z;
  const int r0 = blockIdx.y*32, c0 = blockIdx.x*32;
  const int tx = threadIdx.x & 31, ty = threadIdx.x >> 5;
  const u16* s = src + b*ib;
  #pragma unroll
  for (int rr = ty; rr < 32; rr += 8){
    int r = r0 + rr, c = c0 + tx;
    tile[rr][tx] = (r < R && c < Cc) ? s[(long long)r*ir + c] : (u16)0;
  }
  __syncthreads();
  u16* d = dst + b*ob;
  #pragma unroll
  for (int cc = ty; cc < 32; cc += 8){
    int c = c0 + cc, r = r0 + tx;
    if (r < Rpad && c < Cc) d[(long long)c*oc + r] = tile[tx][cc];
  }
}

// ---------------- the 128x128 GEMM ----------------
// MODE 0: C = A0*B0^T
// MODE 1: C = A0*B0^T + SGN * A1*B1^T
// EPI 0: bf16 raw; 1: bf16 gelu(v); 2: bf16 gelu(v+bias); 3: bf16 gelu(v+bias)+addsrc(bf16)
struct GemmP {
  const u16 *A0, *A1, *B0, *B1;
  u16 *C0;
  const float *bias;
  const u16 *addsrc;
  int M, N, K;
  int lda, ldb, ldc;
  long long bsA, bsB, bsC;
};

__device__ __forceinline__ void gl2lds16(const u16* g, u16* l){
  __builtin_amdgcn_global_load_lds(
      (const __attribute__((address_space(1))) u32*)((const void*)g),
      (__attribute__((address_space(3))) u32*)((void*)l),
      16, 0, 0);
}

// slow (edge) staging: same swizzled layout, bounds-checked, zero-filled
__device__ __forceinline__ void stage_slow(u16* sT, const u16* g, long long ld,
                                           int row0, int rmax, int k0, int K, int tid){
  #pragma unroll
  for (int h = 0; h < 2; h++){
    int s = tid + h*256;
    int row = s >> 2;
    int col = (((s & 3) ^ ((s >> 3) & 3)) << 3);
    int grow = row0 + row;
    u16 v[8];
    #pragma unroll
    for (int e = 0; e < 8; e++){
      int gc = k0 + col + e;
      v[e] = (grow < rmax && gc < K) ? g[(long long)grow*ld + gc] : (u16)0;
    }
    *(uint4*)(sT + s*8) = *(const uint4*)v;
  }
}

template<int MODE, int EPI, int SGN>
__global__ __launch_bounds__(256, MODE==1 ? 2 : 3)
void g128(GemmP p){
  __shared__ u16 sA0[4096];
  __shared__ u16 sB0[4096];
  __shared__ u16 sA1[MODE==1 ? 4096 : 8];
  __shared__ u16 sB1[MODE==1 ? 4096 : 8];

  const int tid = threadIdx.x;
  const long long bz = blockIdx.z;
  const int row0 = blockIdx.y*128, col0 = blockIdx.x*128;
  const int lane = tid & 63, wid = tid >> 6;
  const int wr = wid >> 1, wc = wid & 1;
  const int quad = lane >> 4, l15 = lane & 15;

  const u16* Ag0 = p.A0 + bz*p.bsA;
  const u16* Bg0 = p.B0 + bz*p.bsB;
  const u16* Ag1 = (MODE==1) ? p.A1 + bz*p.bsA : nullptr;
  const u16* Bg1 = (MODE==1) ? p.B1 + bz*p.bsB : nullptr;

  // staging coords (swizzle: chunk pos ^= (row>>1)&3)
  const int srow = tid >> 2;
  const int scol = (((tid & 3) ^ ((tid >> 3) & 3)) << 3);
  const bool fA = (row0 + 128 <= p.M);
  const bool fB = (col0 + 128 <= p.N);
  const u16* pA0 = Ag0 + (long long)(row0 + srow)*p.lda + scol;
  const u16* pB0 = Bg0 + (long long)(col0 + srow)*p.ldb + scol;
  const u16* pA1 = (MODE==1) ? Ag1 + (long long)(row0 + srow)*p.lda + scol : nullptr;
  const u16* pB1 = (MODE==1) ? Bg1 + (long long)(col0 + srow)*p.ldb + scol : nullptr;
  u16* lA = sA0 + tid*8;
  u16* lB = sB0 + tid*8;

  // fragment LDS offsets (constant across K)
  int aoff[4], boff[4];
  #pragma unroll
  for (int i=0;i<4;i++){
    int ar = wr*64 + i*16 + l15;
    aoff[i] = ar*32 + ((quad ^ ((ar>>1)&3))<<3);
    int br = wc*64 + i*16 + l15;
    boff[i] = br*32 + ((quad ^ ((br>>1)&3))<<3);
  }

  f32x4 acc[4][4];
  #pragma unroll
  for (int i=0;i<4;i++)
    #pragma unroll
    for (int j=0;j<4;j++) acc[i][j] = (f32x4){0.f,0.f,0.f,0.f};

  for (int k0 = 0; k0 < p.K; k0 += 32){
    __syncthreads();
    const bool fk = (k0 + 32 <= p.K);
    if (fA && fk){
      gl2lds16(pA0 + k0, lA);
      gl2lds16(pA0 + 64*(long long)p.lda + k0, lA + 2048);
    } else {
      stage_slow(sA0, Ag0, p.lda, row0, p.M, k0, p.K, tid);
    }
    if (fB && fk){
      gl2lds16(pB0 + k0, lB);
      gl2lds16(pB0 + 64*(long long)p.ldb + k0, lB + 2048);
    } else {
      stage_slow(sB0, Bg0, p.ldb, col0, p.N, k0, p.K, tid);
    }
    if (MODE==1){
      if (fA && fk){
        gl2lds16(pA1 + k0, sA1 + tid*8);
        gl2lds16(pA1 + 64*(long long)p.lda + k0, sA1 + tid*8 + 2048);
      } else {
        stage_slow(sA1, Ag1, p.lda, row0, p.M, k0, p.K, tid);
      }
      if (fB && fk){
        gl2lds16(pB1 + k0, sB1 + tid*8);
        gl2lds16(pB1 + 64*(long long)p.ldb + k0, sB1 + tid*8 + 2048);
      } else {
        stage_slow(sB1, Bg1, p.ldb, col0, p.N, k0, p.K, tid);
      }
    }
    __syncthreads();

    bf16x8 a0[4], b0[4];
    #pragma unroll
    for (int i=0;i<4;i++){
      a0[i] = *(const bf16x8*)&sA0[aoff[i]];
      b0[i] = *(const bf16x8*)&sB0[boff[i]];
    }
    if (MODE==1){
      bf16x8 a1[4], b1[4];
      #pragma unroll
      for (int i=0;i<4;i++){
        a1[i] = *(const bf16x8*)&sA1[aoff[i]];
        b1[i] = *(const bf16x8*)&sB1[boff[i]];
      }
      if (SGN < 0){
        u32* u = (u32*)a1;
        #pragma unroll
        for (int r=0;r<16;r++) u[r] ^= 0x80008000u;
      }
      #pragma unroll
      for (int i=0;i<4;i++)
        #pragma unroll
        for (int j=0;j<4;j++){
          acc[i][j] = __builtin_amdgcn_mfma_f32_16x16x32_bf16(a0[i], b0[j], acc[i][j], 0,0,0);
          acc[i][j] = __builtin_amdgcn_mfma_f32_16x16x32_bf16(a1[i], b1[j], acc[i][j], 0,0,0);
        }
    } else {
      #pragma unroll
      for (int i=0;i<4;i++)
        #pragma unroll
        for (int j=0;j<4;j++)
          acc[i][j] = __builtin_amdgcn_mfma_f32_16x16x32_bf16(a0[i], b0[j], acc[i][j], 0,0,0);
    }
  }

  const long long cb = bz * p.bsC;
  #pragma unroll
  for (int i=0;i<4;i++){
    const int gr0 = row0 + wr*64 + i*16 + quad*4;
    #pragma unroll
    for (int j=0;j<4;j++){
      const int gc = col0 + wc*64 + j*16 + l15;
      if (gc >= p.N) continue;
      const float bval = (EPI==2 || EPI==3) ? p.bias[gc] : 0.0f;
      #pragma unroll
      for (int r=0;r<4;r++){
        const int gr = gr0 + r;
        if (gr >= p.M) continue;
        const long long ci = cb + (long long)gr * p.ldc + gc;
        float v = acc[i][j][r];
        if (EPI==0)      p.C0[ci] = f2b(v);
        else if (EPI==1) p.C0[ci] = f2b(gelu_exact(v));
        else if (EPI==2) p.C0[ci] = f2b(gelu_exact(v + bval));
        else             p.C0[ci] = f2b(gelu_exact(v + bval) + b2f(p.addsrc[ci]));
      }
    }
  }
}

// ---------------- instance-norm reduction + final epilogue ----------------
__global__ __launch_bounds__(256) void k_red(const u16* __restrict__ y2,
                                             float* __restrict__ gs, float* __restrict__ gss){
  int t = threadIdx.x;
  long long r0 = (long long)blockIdx.x * 256;
  float s = 0.f, ss = 0.f;
  for (int r=0;r<256;r++){
    float v = b2f(y2[(r0 + r)*256 + t]);
    s += v; ss += v*v;
  }
  atomicAdd(&gs[t], s);
  atomicAdd(&gss[t], ss);
}
// out[c,j,n] = (y2[n,j,c]-mu)*rsqrt(var+eps)*gamma + beta + x[c,j,n]
__global__ __launch_bounds__(256) void k_out(const u16* __restrict__ y2, const float* __restrict__ x,
                                             const float* __restrict__ gs, const float* __restrict__ gss,
                                             const float* __restrict__ gamma, const float* __restrict__ beta,
                                             float* __restrict__ out){
  __shared__ float tile[32][33];
  const int j = blockIdx.z;
  const int n0 = blockIdx.x*32, c0 = blockIdx.y*32;
  const int tx = threadIdx.x & 31, ty = threadIdx.x >> 5;
  #pragma unroll
  for (int nn = ty; nn < 32; nn += 8){
    int n = n0 + nn, c = c0 + tx;
    tile[nn][tx] = b2f(y2[(long long)n*65536 + j*256 + c]);
  }
  __syncthreads();
  #pragma unroll
  for (int cc = ty; cc < 32; cc += 8){
    int c = c0 + cc, n = n0 + tx;
    float mu = gs[c]*(1.0f/131072.0f);
    float var = gss[c]*(1.0f/131072.0f) - mu*mu;
    float rs = rsqrtf(var + 1e-3f);
    long long oi = (long long)c*131072 + (long long)j*512 + n;
    out[oi] = (tile[tx][cc] - mu)*rs*gamma[c] + beta[c] + x[oi];
  }
}

// ---------------- host ----------------
extern "C" void kernel_launch(void* const* d_in, const int* in_sizes, int n_in,
                              void* d_out, int out_size, void* d_ws, size_t ws_size,
                              hipStream_t stream){
  (void)in_sizes; (void)n_in; (void)out_size; (void)ws_size;
  const float* x     = (const float*)d_in[0];
  const float* legf  = (const float*)d_in[1];
  const float* wq    = (const float*)d_in[2];
  const float* w_r   = (const float*)d_in[3];
  const float* w_i   = (const float*)d_in[4];
  const float* m1w1  = (const float*)d_in[5];
  const float* m1b1  = (const float*)d_in[6];
  const float* m1w2  = (const float*)d_in[7];
  const float* m1b2  = (const float*)d_in[8];
  const float* m2w1  = (const float*)d_in[9];
  const float* m2b1  = (const float*)d_in[10];
  const float* m2w2  = (const float*)d_in[11];
  const float* m2b2  = (const float*)d_in[12];
  const float* gamma = (const float*)d_in[13];
  const float* beta  = (const float*)d_in[14];

  char* ws = (char*)d_ws;
  const size_t SLOT = 73400320ULL, HS = 36700160ULL;
  char* F  = ws;                    // small fixed region (4MB)
  char* SA = ws + 4194304ULL;
  char* SB = SA + SLOT;
  char* SC = SB + SLOT;
  char* SD = SC + SLOT;             // total ~298MB

  u16* Tc   = (u16*)(F + 0x000000);
  u16* Ts   = (u16*)(F + 0x050000);
  u16* tabr = (u16*)(F + 0x0A0000);
  u16* tabi = (u16*)(F + 0x0F0000);
  u16* w1t  = (u16*)(F + 0x140000);
  u16* w2t  = (u16*)(F + 0x160000);
  u16* w3t  = (u16*)(F + 0x180000);
  u16* w4t  = (u16*)(F + 0x1A0000);
  float* gsum = (float*)(F + 0x1C0000);
  float* gssq = (float*)(F + 0x1C0400);

  u16* xT   = (u16*)SA;            // (n,j,c) bf16, lives until MLP1a
  u16* x_bf = (u16*)SB;            // (c,j,n) bf16
  u16* lw   = (u16*)SC;            // (l,m,j) bf16
  u16* Fr2  = (u16*)SD;            // (m,c,j) bf16
  u16* Fi2  = (u16*)(SD + HS);
  u16* hr3  = (u16*)SB;            // (m,l,c) bf16  (over x_bf)
  u16* hi3  = (u16*)(SB + HS);
  u16* Wr2  = (u16*)SD;            // (l,f,c) bf16  (over F2)
  u16* Wi2  = (u16*)(SD + HS);
  u16* xs3r = (u16*)SC;            // (l,f,m) ld 264 (over lw)
  u16* xs3i = (u16*)(SC + HS);
  u16* legT = (u16*)SB;            // (m,j,l) bf16  (over h3, after stage 3)
  u16* xs4r = (u16*)SD;            // (m,f,l)       (over W2)
  u16* xs4i = (u16*)(SD + HS);
  u16* Gr5  = (u16*)SC;            // (m,f,j)       (over xs3)
  u16* Gi5  = (u16*)(SC + HS);
  u16* Gr6  = (u16*)SD;            // (j,f,m) ld 264, rows 257..263 zero (over xs4)
  u16* Gi6  = (u16*)(SD + HS);
  u16* g6   = (u16*)SB;            // (n,j,f) bf16  (over legT)
  u16* h1   = (u16*)SD;            // (p,c) bf16    (over G6)
  u16* addb = (u16*)SA;            // (p,c) bf16    (over xT)
  u16* h2   = (u16*)SD;            // (over h1)
  u16* y2   = (u16*)SB;            // (p,c) bf16    (over g6)

  auto grid_of = [](int M, int N, int B){
    return dim3((unsigned)((N+127)/128), (unsigned)((M+127)/128), (unsigned)B);
  };

  // --- precompute ---
  k_ftab<<<dim3(514), dim3(256), 0, stream>>>(Tc, Ts);
  k_itab<<<dim3(528), dim3(256), 0, stream>>>(tabr, tabi);
  tr_f32b<false><<<dim3(8,8,1), dim3(256), 0, stream>>>(m1w1, w1t, nullptr, 256,256, 256,0, 256,0);
  tr_f32b<false><<<dim3(8,8,1), dim3(256), 0, stream>>>(m1w2, w2t, nullptr, 256,256, 256,0, 256,0);
  tr_f32b<false><<<dim3(8,8,1), dim3(256), 0, stream>>>(m2w1, w3t, nullptr, 256,256, 256,0, 256,0);
  tr_f32b<false><<<dim3(8,8,1), dim3(256), 0, stream>>>(m2w2, w4t, nullptr, 256,256, 256,0, 256,0);
  tr_f32b<true><<<dim3(16,8,256), dim3(256), 0, stream>>>(x, xT, x_bf, 256,512, 131072,512, 65536,256);
  k_lw<<<dim3(65792), dim3(256), 0, stream>>>(legf, wq, lw, 256*257*256);

  // --- stage 1: rfft. Fr/Fi (m,c,j) = T(m,n) * x_bf^T ---
  {
    GemmP p{Tc, nullptr, x_bf, nullptr, Fr2, nullptr, nullptr,
            257, 65536, 512, 512, 512, 65536, 0, 0, 0};
    g128<0,0,1><<<grid_of(257,65536,1), dim3(256), 0, stream>>>(p);
    p.A0 = Ts; p.C0 = Fi2;
    g128<0,0,1><<<grid_of(257,65536,1), dim3(256), 0, stream>>>(p);
  }
  // --- stage 2: Legendre fwd, batched over m: h(m,l,c) = lw_m(l,j) * F_m(c,j)^T ---
  {
    GemmP p{lw, nullptr, Fr2, nullptr, hr3, nullptr, nullptr,
            256, 256, 256, 65792, 256, 256, 256, 65536, 65536};
    g128<0,0,1><<<grid_of(256,256,257), dim3(256), 0, stream>>>(p);
    p.B0 = Fi2; p.C0 = hi3;
    g128<0,0,1><<<grid_of(256,256,257), dim3(256), 0, stream>>>(p);
  }
  // --- filters (after F2 dead) ---
  k_interp<<<dim3(65536), dim3(256), 0, stream>>>(w_r, w_i, Wr2, Wi2);
  // --- stage 3: complex filter, batched over l: xs(l,f,m) = W_l(f,c) * h_l(m,c)^T ---
  {
    GemmP p{Wr2, Wi2, hr3, hi3, xs3r, nullptr, nullptr,
            256, 257, 256, 256, 65536, 264, 65536, 256, 67584};
    g128<1,0,-1><<<grid_of(256,257,256), dim3(256), 0, stream>>>(p);  // re: Wr*hr - Wi*hi
    p.B0 = hi3; p.B1 = hr3; p.C0 = xs3i;
    g128<1,0, 1><<<grid_of(256,257,256), dim3(256), 0, stream>>>(p);  // im: Wr*hi + Wi*hr
  }
  // --- legT (m,j,l) (after h3 dead) ---
  tr_f32b<false><<<dim3(8,8,257), dim3(256), 0, stream>>>(legf, legT, nullptr, 256,256, 65792,256, 256,65536);
  // --- xs (l,f,m) -> (m,f,l) ---
  tr_b16<<<dim3(9,8,256), dim3(256), 0, stream>>>(xs3r, xs4r, 256,256,257, 67584,264, 65536,256);
  tr_b16<<<dim3(9,8,256), dim3(256), 0, stream>>>(xs3i, xs4i, 256,256,257, 67584,264, 65536,256);
  // --- stage 4: Legendre inv, batched over m: G(m,f,j) = xs_m(f,l) * legT_m(j,l)^T ---
  {
    GemmP p{xs4r, nullptr, legT, nullptr, Gr5, nullptr, nullptr,
            256, 256, 256, 256, 256, 256, 65536, 65536, 65536};
    g128<0,0,1><<<grid_of(256,256,257), dim3(256), 0, stream>>>(p);
    p.A0 = xs4i; p.C0 = Gi5;
    g128<0,0,1><<<grid_of(256,256,257), dim3(256), 0, stream>>>(p);
  }
  // --- G (m,f,j) -> (j,f,m), zero-pad m to 264 ---
  tr_b16<<<dim3(8,9,256), dim3(256), 0, stream>>>(Gr5, Gr6, 257,264,256, 65536,256, 67584,264);
  tr_b16<<<dim3(8,9,256), dim3(256), 0, stream>>>(Gi5, Gi6, 257,264,256, 65536,256, 67584,264);
  // --- stage 5: irfft + gelu: g6(n, j*256+f) = gelu(tabr(n,m)*Gr6^T + tabi(n,m)*Gi6^T) ---
  {
    GemmP p{tabr, tabi, Gr6, Gi6, g6, nullptr, nullptr,
            512, 65536, 264, 264, 264, 65536, 0, 0, 0};
    g128<1,1,1><<<grid_of(512,65536,1), dim3(256), 0, stream>>>(p);
  }
  // --- MLP1 ---
  {
    GemmP p{xT, nullptr, w1t, nullptr, h1, m1b1, nullptr,
            131072, 256, 256, 256, 256, 256, 0, 0, 0};
    g128<0,2,1><<<grid_of(131072,256,1), dim3(256), 0, stream>>>(p);
    p.A0 = h1; p.B0 = w2t; p.C0 = addb; p.bias = m1b2; p.addsrc = g6;
    g128<0,3,1><<<grid_of(131072,256,1), dim3(256), 0, stream>>>(p);
  }
  // --- MLP2 ---
  {
    GemmP p{addb, nullptr, w3t, nullptr, h2, m2b1, nullptr,
            131072, 256, 256, 256, 256, 256, 0, 0, 0};
    g128<0,2,1><<<grid_of(131072,256,1), dim3(256), 0, stream>>>(p);
    p.A0 = h2; p.B0 = w4t; p.C0 = y2; p.bias = m2b2;
    g128<0,2,1><<<grid_of(131072,256,1), dim3(256), 0, stream>>>(p);
  }
  // --- instance norm + residual ---
  hipMemsetAsync(gsum, 0, 2048, stream);
  k_red<<<dim3(512), dim3(256), 0, stream>>>(y2, gsum, gssq);
  k_out<<<dim3(16,8,256), dim3(256), 0, stream>>>(y2, x, gsum, gssq, gamma, beta, (float*)d_out);
}

// Round 3
// 1346.236 us; speedup vs baseline: 1.2795x; 1.1954x over previous
//
#include <hip/hip_runtime.h>

// SFNO block on MI355X. All heavy stages as bf16 MFMA GEMMs (C = A * B^T),
// fp32 accumulate, 128x128 tiles, global_load_lds staging, XOR-swizzled LDS.
// Fused dual/complex product modes. Sizes: C=256, NLAT=256, NLON=512, L=256,
// M=257 (rfft rows padded to 384, irfft K padded to 288), NREF=64.

typedef __bf16 bf16x8 __attribute__((ext_vector_type(8)));
typedef float f32x4 __attribute__((ext_vector_type(4)));
typedef unsigned short u16;
typedef unsigned int u32;

__device__ __forceinline__ u16 f2b(float f){
  u32 u = __float_as_uint(f);
  u32 r = (u + 0x7FFFu + ((u >> 16) & 1u)) >> 16;  // round-to-nearest-even
  return (u16)r;
}
__device__ __forceinline__ float b2f(u16 h){
  return __uint_as_float(((u32)h) << 16);
}
__device__ __forceinline__ float gelu_exact(float v){
  return 0.5f * v * (1.0f + erff(v * 0.7071067811865475f));
}

// ---------------- small precompute kernels ----------------

// forward DFT tables (384 x 512) bf16, rows >=257 zero: Tc=cos, Ts=-sin
__global__ __launch_bounds__(256) void k_ftab(u16* Tc, u16* Ts){
  int i = blockIdx.x*256 + threadIdx.x;
  if (i >= 384*512) return;
  int m = i >> 9, n = i & 511;
  if (m >= 257){ Tc[i]=0; Ts[i]=0; return; }
  int r = (m*n) & 511;
  float th = (float)r * (6.283185307179586f/512.0f);
  Tc[i] = f2b(cosf(th));
  Ts[i] = f2b(-sinf(th));
}
// inverse tables (512 x 288), cols >=257 zero. cm=1 for m in {0,256}, else 2; /512.
__global__ __launch_bounds__(256) void k_itab(u16* tr, u16* ti){
  int i = blockIdx.x*256 + threadIdx.x;
  if (i >= 512*288) return;
  int n = i / 288, m = i % 288;
  if (m >= 257){ tr[i]=0; ti[i]=0; return; }
  int r = (n*m) & 511;
  float th = (float)r * (6.283185307179586f/512.0f);
  float cm = (m==0 || m==256) ? (1.0f/512.0f) : (2.0f/512.0f);
  tr[i] = f2b(cm*cosf(th));
  ti[i] = f2b(-cm*sinf(th));
}
// lw[l,m,j] = legfuncs[l,m,j]*wquad[j] -> bf16
__global__ __launch_bounds__(256) void k_lw(const float* __restrict__ leg,
                                            const float* __restrict__ wq,
                                            u16* __restrict__ lw, int total){
  int i = blockIdx.x*256 + threadIdx.x;
  if (i >= total) return;
  lw[i] = f2b(leg[i]*wq[i & 255]);
}
// interpolated filters, scaled by sqrt(1+l)/256, layout (l,f,c) bf16.
// block = (f, c-chunk of 64); coalesced 16KB LDS stage of w[f, c0:c0+64, :].
__global__ __launch_bounds__(256) void k_interp(const float* __restrict__ wr,
                                                const float* __restrict__ wi,
                                                u16* __restrict__ Wr2, u16* __restrict__ Wi2){
  __shared__ float sr[64][65], si[64][65];
  const int f = blockIdx.x;
  const int c0 = blockIdx.y * 64;
  const float* gr = wr + ((long long)f*256 + c0)*64;
  const float* gi = wi + ((long long)f*256 + c0)*64;
  for (int t = threadIdx.x*4; t < 4096; t += 1024){
    float4 vr = *(const float4*)(gr + t);
    float4 vi = *(const float4*)(gi + t);
    int cc = t >> 6, k = t & 63;
    sr[cc][k]=vr.x; sr[cc][k+1]=vr.y; sr[cc][k+2]=vr.z; sr[cc][k+3]=vr.w;
    si[cc][k]=vi.x; si[cc][k+1]=vi.y; si[cc][k+2]=vi.z; si[cc][k+3]=vi.w;
  }
  __syncthreads();
  const int lane_c = threadIdx.x & 63;
  const int lgrp = threadIdx.x >> 6;
  for (int l = lgrp; l < 256; l += 4){
    float pos = (float)l * (63.0f/255.0f);
    int i0 = min((int)pos, 62);
    float fr = pos - (float)i0;
    float s = sqrtf(1.0f + (float)l) * (1.0f/256.0f);
    long long o = (long long)l*65536 + f*256 + c0 + lane_c;
    Wr2[o] = f2b((sr[lane_c][i0]*(1.0f-fr) + sr[lane_c][i0+1]*fr)*s);
    Wi2[o] = f2b((si[lane_c][i0]*(1.0f-fr) + si[lane_c][i0+1]*fr)*s);
  }
}

// ---------------- generic tiled transposes ----------------
template<bool DUAL>
__global__ __launch_bounds__(256)
void tr_f32b(const float* __restrict__ src, u16* __restrict__ dst, u16* __restrict__ copy,
             int R, int Cc, long long ir, long long ib, long long oc, long long ob){
  __shared__ float tile[32][33];
  const long long b = blockIdx.z;
  const int r0 = blockIdx.y*32, c0 = blockIdx.x*32;
  const int tx = threadIdx.x & 31, ty = threadIdx.x >> 5;
  const float* s = src + b*ib;
  #pragma unroll
  for (int rr = ty; rr < 32; rr += 8){
    int r = r0 + rr, c = c0 + tx;
    float v = 0.0f;
    if (r < R && c < Cc){
      v = s[(long long)r*ir + c];
      if (DUAL) copy[b*ib + (long long)r*ir + c] = f2b(v);
    }
    tile[rr][tx] = v;
  }
  __syncthreads();
  u16* d = dst + b*ob;
  #pragma unroll
  for (int cc = ty; cc < 32; cc += 8){
    int c = c0 + cc, r = r0 + tx;
    if (r < R && c < Cc) d[(long long)c*oc + r] = f2b(tile[tx][cc]);
  }
}
// bf16 transpose; zero-pads dst rows r in [R, Rpad)
__global__ __launch_bounds__(256)
void tr_b16(const u16* __restrict__ src, u16* __restrict__ dst,
            int R, int Rpad, int Cc, long long ir, long long ib, long long oc, long long ob){
  __shared__ u16 tile[32][34];
  const long long b = blockIdx.z;
  const int r0 = blockIdx.y*32, c0 = blockIdx.x*32;
  const int tx = threadIdx.x & 31, ty = threadIdx.x >> 5;
  const u16* s = src + b*ib;
  #pragma unroll
  for (int rr = ty; rr < 32; rr += 8){
    int r = r0 + rr, c = c0 + tx;
    tile[rr][tx] = (r < R && c < Cc) ? s[(long long)r*ir + c] : (u16)0;
  }
  __syncthreads();
  u16* d = dst + b*ob;
  #pragma unroll
  for (int cc = ty; cc < 32; cc += 8){
    int c = c0 + cc, r = r0 + tx;
    if (r < Rpad && c < Cc) d[(long long)c*oc + r] = tile[tx][cc];
  }
}

// ---------------- the 128x128 GEMM ----------------
// MODE 0: C0 = A0*B0^T
// MODE 1: C0 = A0*B0^T + A1*B1^T
// MODE 2: C0 = A0*B0^T ; C1 = A0*B1^T          (shared A)
// MODE 3: C0 = A0*B0^T ; C1 = A1*B0^T          (shared B)
// MODE 4: C0 = A0*B0^T - A1*B1^T ; C1 = A0*B1^T + A1*B0^T   (complex)
// EPI 0: bf16 raw; 1: bf16 gelu(v); 2: bf16 gelu(v+bias); 3: bf16 gelu(v+bias)+addsrc
struct GemmP {
  const u16 *A0, *A1, *B0, *B1;
  u16 *C0, *C1;
  const float *bias;
  const u16 *addsrc;
  int M, Mout, N, K;           // M = staging row extent (padded); Mout = C rows
  int lda, ldb, ldc;
  long long bsA, bsB, bsC;
};

__device__ __forceinline__ void gl2lds16(const u16* g, u16* l){
  __builtin_amdgcn_global_load_lds(
      (const __attribute__((address_space(1))) u32*)((const void*)g),
      (__attribute__((address_space(3))) u32*)((void*)l),
      16, 0, 0);
}

// slow (edge) staging: same swizzled layout, bounds-checked, zero-filled
__device__ __forceinline__ void stage_slow(u16* sT, const u16* g, long long ld,
                                           int row0, int rmax, int k0, int K, int tid){
  #pragma unroll
  for (int h = 0; h < 2; h++){
    int s = tid + h*256;
    int row = s >> 2;
    int col = (((s & 3) ^ ((s >> 3) & 3)) << 3);
    int grow = row0 + row;
    u16 v[8];
    #pragma unroll
    for (int e = 0; e < 8; e++){
      int gc = k0 + col + e;
      v[e] = (grow < rmax && gc < K) ? g[(long long)grow*ld + gc] : (u16)0;
    }
    *(uint4*)(sT + s*8) = *(const uint4*)v;
  }
}

template<int MODE, int EPI>
__global__ __launch_bounds__(256, (MODE==0) ? 3 : 2)
void g128(GemmP p){
  constexpr int NA = (MODE==0 || MODE==2) ? 1 : 2;
  constexpr int NB = (MODE==0 || MODE==3) ? 1 : 2;
  constexpr bool DUAL = (MODE >= 2);
  __shared__ u16 sA[NA][4096];
  __shared__ u16 sB[NB][4096];

  const int tid = threadIdx.x;
  const long long bz = blockIdx.z;
  const int row0 = blockIdx.y*128, col0 = blockIdx.x*128;
  const int lane = tid & 63, wid = tid >> 6;
  const int wr = wid >> 1, wc = wid & 1;
  const int quad = lane >> 4, l15 = lane & 15;

  const u16* Ag[NA]; const u16* Bg[NB];
  Ag[0] = p.A0 + bz*p.bsA;
  if (NA == 2) Ag[1] = p.A1 + bz*p.bsA;
  Bg[0] = p.B0 + bz*p.bsB;
  if (NB == 2) Bg[1] = p.B1 + bz*p.bsB;

  const int srow = tid >> 2;
  const int scol = (((tid & 3) ^ ((tid >> 3) & 3)) << 3);
  const bool fA = (row0 + 128 <= p.M);
  const bool fB = (col0 + 128 <= p.N);

  int aoff[4], boff[4];
  #pragma unroll
  for (int i=0;i<4;i++){
    int ar = wr*64 + i*16 + l15;
    aoff[i] = ar*32 + ((quad ^ ((ar>>1)&3))<<3);
    int br = wc*64 + i*16 + l15;
    boff[i] = br*32 + ((quad ^ ((br>>1)&3))<<3);
  }

  f32x4 acc0[4][4], acc1[4][4];
  #pragma unroll
  for (int i=0;i<4;i++)
    #pragma unroll
    for (int j=0;j<4;j++){
      acc0[i][j] = (f32x4){0.f,0.f,0.f,0.f};
      if (DUAL) acc1[i][j] = (f32x4){0.f,0.f,0.f,0.f};
    }

  for (int k0 = 0; k0 < p.K; k0 += 32){
    __syncthreads();
    const bool fk = (k0 + 32 <= p.K);
    #pragma unroll
    for (int t=0;t<NA;t++){
      if (fA && fk){
        const u16* g = Ag[t] + (long long)(row0 + srow)*p.lda + scol + k0;
        gl2lds16(g, &sA[t][tid*8]);
        gl2lds16(g + 64LL*p.lda, &sA[t][tid*8 + 2048]);
      } else stage_slow(&sA[t][0], Ag[t], p.lda, row0, p.M, k0, p.K, tid);
    }
    #pragma unroll
    for (int t=0;t<NB;t++){
      if (fB && fk){
        const u16* g = Bg[t] + (long long)(col0 + srow)*p.ldb + scol + k0;
        gl2lds16(g, &sB[t][tid*8]);
        gl2lds16(g + 64LL*p.ldb, &sB[t][tid*8 + 2048]);
      } else stage_slow(&sB[t][0], Bg[t], p.ldb, col0, p.N, k0, p.K, tid);
    }
    __syncthreads();

    bf16x8 a[NA][4], b[NB][4];
    #pragma unroll
    for (int t=0;t<NA;t++)
      #pragma unroll
      for (int i=0;i<4;i++) a[t][i] = *(const bf16x8*)&sA[t][aoff[i]];
    #pragma unroll
    for (int t=0;t<NB;t++)
      #pragma unroll
      for (int i=0;i<4;i++) b[t][i] = *(const bf16x8*)&sB[t][boff[i]];

    bf16x8 an[4];
    if (MODE == 4){
      #pragma unroll
      for (int i=0;i<4;i++){
        an[i] = a[1][i];
        u32* u = (u32*)&an[i];
        #pragma unroll
        for (int r=0;r<4;r++) u[r] ^= 0x80008000u;
      }
    }

    #pragma unroll
    for (int i=0;i<4;i++){
      #pragma unroll
      for (int j=0;j<4;j++){
        if (MODE == 0){
          acc0[i][j] = __builtin_amdgcn_mfma_f32_16x16x32_bf16(a[0][i], b[0][j], acc0[i][j], 0,0,0);
        } else if (MODE == 1){
          acc0[i][j] = __builtin_amdgcn_mfma_f32_16x16x32_bf16(a[0][i], b[0][j], acc0[i][j], 0,0,0);
          acc0[i][j] = __builtin_amdgcn_mfma_f32_16x16x32_bf16(a[1][i], b[1][j], acc0[i][j], 0,0,0);
        } else if (MODE == 2){
          acc0[i][j] = __builtin_amdgcn_mfma_f32_16x16x32_bf16(a[0][i], b[0][j], acc0[i][j], 0,0,0);
          acc1[i][j] = __builtin_amdgcn_mfma_f32_16x16x32_bf16(a[0][i], b[1][j], acc1[i][j], 0,0,0);
        } else if (MODE == 3){
          acc0[i][j] = __builtin_amdgcn_mfma_f32_16x16x32_bf16(a[0][i], b[0][j], acc0[i][j], 0,0,0);
          acc1[i][j] = __builtin_amdgcn_mfma_f32_16x16x32_bf16(a[1][i], b[0][j], acc1[i][j], 0,0,0);
        } else {
          acc0[i][j] = __builtin_amdgcn_mfma_f32_16x16x32_bf16(a[0][i], b[0][j], acc0[i][j], 0,0,0);
          acc0[i][j] = __builtin_amdgcn_mfma_f32_16x16x32_bf16(an[i],   b[1][j], acc0[i][j], 0,0,0);
          acc1[i][j] = __builtin_amdgcn_mfma_f32_16x16x32_bf16(a[0][i], b[1][j], acc1[i][j], 0,0,0);
          acc1[i][j] = __builtin_amdgcn_mfma_f32_16x16x32_bf16(a[1][i], b[0][j], acc1[i][j], 0,0,0);
        }
      }
    }
  }

  const long long cb = bz * p.bsC;
  #pragma unroll
  for (int i=0;i<4;i++){
    const int gr0 = row0 + wr*64 + i*16 + quad*4;
    #pragma unroll
    for (int j=0;j<4;j++){
      const int gc = col0 + wc*64 + j*16 + l15;
      if (gc >= p.N) continue;
      const float bval = (EPI==2 || EPI==3) ? p.bias[gc] : 0.0f;
      #pragma unroll
      for (int r=0;r<4;r++){
        const int gr = gr0 + r;
        if (gr >= p.Mout) continue;
        const long long ci = cb + (long long)gr * p.ldc + gc;
        float v = acc0[i][j][r];
        if (EPI==0){
          p.C0[ci] = f2b(v);
          if (DUAL) p.C1[ci] = f2b(acc1[i][j][r]);
        }
        else if (EPI==1) p.C0[ci] = f2b(gelu_exact(v));
        else if (EPI==2) p.C0[ci] = f2b(gelu_exact(v + bval));
        else             p.C0[ci] = f2b(gelu_exact(v + bval) + b2f(p.addsrc[ci]));
      }
    }
  }
}

// ---------------- instance-norm reduction + final epilogue ----------------
__global__ __launch_bounds__(256) void k_red(const u16* __restrict__ y2,
                                             float* __restrict__ gs, float* __restrict__ gss){
  int t = threadIdx.x;
  long long r0 = (long long)blockIdx.x * 256;
  float s = 0.f, ss = 0.f;
  for (int r=0;r<256;r++){
    float v = b2f(y2[(r0 + r)*256 + t]);
    s += v; ss += v*v;
  }
  atomicAdd(&gs[t], s);
  atomicAdd(&gss[t], ss);
}
// out[c,j,n] = (y2[n,j,c]-mu)*rsqrt(var+eps)*gamma + beta + x[c,j,n]
__global__ __launch_bounds__(256) void k_out(const u16* __restrict__ y2, const float* __restrict__ x,
                                             const float* __restrict__ gs, const float* __restrict__ gss,
                                             const float* __restrict__ gamma, const float* __restrict__ beta,
                                             float* __restrict__ out){
  __shared__ float tile[32][33];
  const int j = blockIdx.z;
  const int n0 = blockIdx.x*32, c0 = blockIdx.y*32;
  const int tx = threadIdx.x & 31, ty = threadIdx.x >> 5;
  #pragma unroll
  for (int nn = ty; nn < 32; nn += 8){
    int n = n0 + nn, c = c0 + tx;
    tile[nn][tx] = b2f(y2[(long long)n*65536 + j*256 + c]);
  }
  __syncthreads();
  #pragma unroll
  for (int cc = ty; cc < 32; cc += 8){
    int c = c0 + cc, n = n0 + tx;
    float mu = gs[c]*(1.0f/131072.0f);
    float var = gss[c]*(1.0f/131072.0f) - mu*mu;
    float rs = rsqrtf(var + 1e-3f);
    long long oi = (long long)c*131072 + (long long)j*512 + n;
    out[oi] = (tile[tx][cc] - mu)*rs*gamma[c] + beta[c] + x[oi];
  }
}

// ---------------- host ----------------
extern "C" void kernel_launch(void* const* d_in, const int* in_sizes, int n_in,
                              void* d_out, int out_size, void* d_ws, size_t ws_size,
                              hipStream_t stream){
  (void)in_sizes; (void)n_in; (void)out_size; (void)ws_size;
  const float* x     = (const float*)d_in[0];
  const float* legf  = (const float*)d_in[1];
  const float* wq    = (const float*)d_in[2];
  const float* w_r   = (const float*)d_in[3];
  const float* w_i   = (const float*)d_in[4];
  const float* m1w1  = (const float*)d_in[5];
  const float* m1b1  = (const float*)d_in[6];
  const float* m1w2  = (const float*)d_in[7];
  const float* m1b2  = (const float*)d_in[8];
  const float* m2w1  = (const float*)d_in[9];
  const float* m2b1  = (const float*)d_in[10];
  const float* m2w2  = (const float*)d_in[11];
  const float* m2b2  = (const float*)d_in[12];
  const float* gamma = (const float*)d_in[13];
  const float* beta  = (const float*)d_in[14];

  char* ws = (char*)d_ws;
  // per-slot arena (all concurrent-lifetime maxima):
  const size_t SZ_SA = 67108864ULL;   // xT / addb
  const size_t SZ_SB = 67371008ULL;   // x_bf | hr3+hi3 | legT | g6 | y2
  const size_t SZ_SC = 69206016ULL;   // lw | xs3r+xs3i | Gr5+Gi5
  const size_t SZ_SD = 75497472ULL;   // Fr2+Fi2 | Wr2+Wi2 | xs4 | Gr6+Gi6 | h1/h2
  char* F  = ws;
  char* SA = ws + 4194304ULL;
  char* SB = SA + SZ_SA;
  char* SC = SB + SZ_SB;
  char* SD = SC + SZ_SC;              // end: ~283.4 MB

  u16* Tc   = (u16*)(F + 0x000000);   // 384x512
  u16* Ts   = (u16*)(F + 0x060000);
  u16* tabr = (u16*)(F + 0x0C0000);   // 512x288
  u16* tabi = (u16*)(F + 0x108000);
  u16* w1t  = (u16*)(F + 0x150000);
  u16* w2t  = (u16*)(F + 0x170000);
  u16* w3t  = (u16*)(F + 0x190000);
  u16* w4t  = (u16*)(F + 0x1B0000);
  float* gsum = (float*)(F + 0x1D0000);
  float* gssq = (float*)(F + 0x1D0400);

  const size_t HS = 33685504ULL;      // 257*65536*2
  u16* xT   = (u16*)SA;               // (n,j,c)
  u16* x_bf = (u16*)SB;               // (c,j,n)
  u16* lw   = (u16*)SC;               // (l,m,j)
  u16* Fr2  = (u16*)SD;               // (m,c,j)
  u16* Fi2  = (u16*)(SD + HS);
  u16* hr3  = (u16*)SB;               // (m,l,c)
  u16* hi3  = (u16*)(SB + HS);
  u16* Wr2  = (u16*)SD;               // (l,f,c)
  u16* Wi2  = (u16*)(SD + HS);
  u16* xs3r = (u16*)SC;               // (l,f,m) ld 264
  u16* xs3i = (u16*)(SC + 34603008ULL);
  u16* legT = (u16*)SB;               // (m,j,l)
  u16* xs4r = (u16*)SD;               // (m,f,l)
  u16* xs4i = (u16*)(SD + HS);
  u16* Gr5  = (u16*)SC;               // (m,f,j)
  u16* Gi5  = (u16*)(SC + HS);
  u16* Gr6  = (u16*)SD;               // (j,f,m) ld 288, m>=257 zero
  u16* Gi6  = (u16*)(SD + 37748736ULL);
  u16* g6   = (u16*)SB;               // (n,j,f)
  u16* h1   = (u16*)SD;               // (p,c)
  u16* addb = (u16*)SA;               // (p,c)
  u16* h2   = (u16*)SD;
  u16* y2   = (u16*)SB;               // (p,c)

  // --- precompute ---
  k_ftab<<<dim3(768), dim3(256), 0, stream>>>(Tc, Ts);
  k_itab<<<dim3(576), dim3(256), 0, stream>>>(tabr, tabi);
  tr_f32b<false><<<dim3(8,8,1), dim3(256), 0, stream>>>(m1w1, w1t, nullptr, 256,256, 256,0, 256,0);
  tr_f32b<false><<<dim3(8,8,1), dim3(256), 0, stream>>>(m1w2, w2t, nullptr, 256,256, 256,0, 256,0);
  tr_f32b<false><<<dim3(8,8,1), dim3(256), 0, stream>>>(m2w1, w3t, nullptr, 256,256, 256,0, 256,0);
  tr_f32b<false><<<dim3(8,8,1), dim3(256), 0, stream>>>(m2w2, w4t, nullptr, 256,256, 256,0, 256,0);
  tr_f32b<true><<<dim3(16,8,256), dim3(256), 0, stream>>>(x, xT, x_bf, 256,512, 131072,512, 65536,256);
  k_lw<<<dim3(65792), dim3(256), 0, stream>>>(legf, wq, lw, 256*257*256);

  // --- stage 1: rfft (fused re+im, shared B): Fr/Fi(m,c,j) = Tc/Ts(m,n) * x_bf^T ---
  {
    GemmP p{Tc, Ts, x_bf, nullptr, Fr2, Fi2, nullptr, nullptr,
            384, 257, 65536, 512, 512, 512, 65536, 0, 0, 0};
    g128<3,0><<<dim3(512,3,1), dim3(256), 0, stream>>>(p);
  }
  // --- stage 2: Legendre fwd (fused, shared A), batch m: h(m,l,c) = lw_m(l,j) * F_m(c,j)^T ---
  {
    GemmP p{lw, nullptr, Fr2, Fi2, hr3, hi3, nullptr, nullptr,
            256, 256, 256, 256, 65792, 256, 256, 256, 65536, 65536};
    g128<2,0><<<dim3(2,2,257), dim3(256), 0, stream>>>(p);
  }
  // --- filters (after F2 dead) ---
  k_interp<<<dim3(256,4), dim3(256), 0, stream>>>(w_r, w_i, Wr2, Wi2);
  // --- stage 3: complex filter, batch l: xs = W_l * h_l^H-ish (4-product fused) ---
  {
    GemmP p{Wr2, Wi2, hr3, hi3, xs3r, xs3i, nullptr, nullptr,
            256, 256, 257, 256, 256, 65536, 264, 65536, 256, 67584};
    g128<4,0><<<dim3(3,2,256), dim3(256), 0, stream>>>(p);
  }
  // --- legT (m,j,l) ---
  tr_f32b<false><<<dim3(8,8,257), dim3(256), 0, stream>>>(legf, legT, nullptr, 256,256, 65792,256, 256,65536);
  // --- xs (l,f,m) -> (m,f,l) ---
  tr_b16<<<dim3(9,8,256), dim3(256), 0, stream>>>(xs3r, xs4r, 256,256,257, 67584,264, 65536,256);
  tr_b16<<<dim3(9,8,256), dim3(256), 0, stream>>>(xs3i, xs4i, 256,256,257, 67584,264, 65536,256);
  // --- stage 4: Legendre inv (fused, shared B), batch m: G(m,f,j) = xs_m(f,l) * legT_m(j,l)^T ---
  {
    GemmP p{xs4r, xs4i, legT, nullptr, Gr5, Gi5, nullptr, nullptr,
            256, 256, 256, 256, 256, 256, 256, 65536, 65536, 65536};
    g128<3,0><<<dim3(2,2,257), dim3(256), 0, stream>>>(p);
  }
  // --- G (m,f,j) -> (j,f,m), zero-pad m to 288 ---
  tr_b16<<<dim3(8,9,256), dim3(256), 0, stream>>>(Gr5, Gr6, 257,288,256, 65536,256, 73728,288);
  tr_b16<<<dim3(8,9,256), dim3(256), 0, stream>>>(Gi5, Gi6, 257,288,256, 65536,256, 73728,288);
  // --- stage 5: irfft + gelu: g6(n, j*256+f) = gelu(tabr*Gr6^T + tabi*Gi6^T), K=288 all-fast ---
  {
    GemmP p{tabr, tabi, Gr6, Gi6, g6, nullptr, nullptr, nullptr,
            512, 512, 65536, 288, 288, 288, 65536, 0, 0, 0};
    g128<1,1><<<dim3(512,4,1), dim3(256), 0, stream>>>(p);
  }
  // --- MLP1 ---
  {
    GemmP p{xT, nullptr, w1t, nullptr, h1, nullptr, m1b1, nullptr,
            131072, 131072, 256, 256, 256, 256, 256, 0, 0, 0};
    g128<0,2><<<dim3(2,1024,1), dim3(256), 0, stream>>>(p);
    p.A0 = h1; p.B0 = w2t; p.C0 = addb; p.bias = m1b2; p.addsrc = g6;
    g128<0,3><<<dim3(2,1024,1), dim3(256), 0, stream>>>(p);
  }
  // --- MLP2 ---
  {
    GemmP p{addb, nullptr, w3t, nullptr, h2, nullptr, m2b1, nullptr,
            131072, 131072, 256, 256, 256, 256, 256, 0, 0, 0};
    g128<0,2><<<dim3(2,1024,1), dim3(256), 0, stream>>>(p);
    p.A0 = h2; p.B0 = w4t; p.C0 = y2; p.bias = m2b2;
    g128<0,2><<<dim3(2,1024,1), dim3(256), 0, stream>>>(p);
  }
  // --- instance norm + residual ---
  hipMemsetAsync(gsum, 0, 2048, stream);
  k_red<<<dim3(512), dim3(256), 0, stream>>>(y2, gsum, gssq);
  k_out<<<dim3(16,8,256), dim3(256), 0, stream>>>(y2, x, gsum, gssq, gamma, beta, (float*)d_out);
}